// Round 1
// baseline (468.660 us; speedup 1.0000x reference)
//
#include <hip/hip_runtime.h>

// Activation1d (BigVGAN-style anti-aliased snake-beta), fp32.
// x: (B=16, C=512, T=8192). 2x upsample (K=12) -> snake -> 2x downsample.
//
// Derived index math (verified against jax conv_general_dilated semantics):
//   xp[j] = x[clamp(j-5, 0, T-1)]
//   up[2s]   = 2*(f1*x(s+2)+f3*x(s+1)+f5*x(s)+f7*x(s-1)+f9*x(s-2)+f11*x(s-3))
//   up[2s+1] = 2*(f0*x(s+3)+f2*x(s+2)+f4*x(s+1)+f6*x(s)+f8*x(s-1)+f10*x(s-2))
//     (x(g) means x[clamp(g,0,T-1)])
//   act[t] = up[t] + (1/(exp(beta)+1e-9)) * sin(up[t]*exp(alpha))^2
//   out[n] = sum_{k=0..11} df[k] * act[clamp(2n+k-5, 0, 2T-1)]
//
// Design: NO LDS (a staged LDS design is ~3x over the HBM roofline on
// ds_read_b32 throughput). Each thread owns W=8 consecutive outputs fully in
// registers: 6x float4 loads cover x[nb-8 .. nb+16); 26 act values; 96 FMA
// down-conv; 2x float4 stores. Only the first/last thread of each row takes
// the generic clamped path (per-tap global loads -> no dynamic register
// indexing -> no scratch).

#define T_LEN 8192
#define C_CH  512
#define B_N   16
#define W     8
#define BLOCK 256

__global__ __launch_bounds__(BLOCK) void act1d_kernel(
    const float* __restrict__ x,
    const float* __restrict__ uf_g,
    const float* __restrict__ df_g,
    const float* __restrict__ alpha,
    const float* __restrict__ beta,
    float* __restrict__ out)
{
    const int T = T_LEN;
    const int bid = blockIdx.x;
    const int row = bid >> 2;          // b*C + c   (4 blocks per row: 4*256*8 = 8192)
    const int chunk = bid & 3;
    const int c = row & (C_CH - 1);
    const int nb = chunk * (BLOCK * W) + (int)threadIdx.x * W;
    const long rowoff = (long)row * T;
    const float* xrow = x + rowoff;

    // filters: uniform indices -> scalar loads. Fold the UP_RATIO=2 gain into uf.
    float uf[12], df[12];
#pragma unroll
    for (int k = 0; k < 12; ++k) { uf[k] = 2.0f * uf_g[k]; df[k] = df_g[k]; }

    const float ea   = __expf(alpha[c]);
    const float invb = 1.0f / (__expf(beta[c]) + 1e-9f);

    float a[26];   // act values at t = 2*nb-5 + j, j in [0,26)

    const bool interior = (nb >= 8) && (nb + 16 <= T);
    if (interior) {
        float xr[24];  // x[nb-8 .. nb+15]
        const float4* xv = (const float4*)(xrow + nb - 8);
#pragma unroll
        for (int k = 0; k < 6; ++k) {
            float4 v = xv[k];
            xr[4*k+0] = v.x; xr[4*k+1] = v.y; xr[4*k+2] = v.z; xr[4*k+3] = v.w;
        }
#pragma unroll
        for (int j = 0; j < 26; ++j) {
            // t = 2*nb - 5 + j ; s = t>>1 = nb + ((j-5)>>1) ; xr[xi] == x[s]
            const int xi = ((j - 5) >> 1) + 8;
            float up;
            if ((j & 1) == 0) {   // t odd
                up = uf[0]*xr[xi+3] + uf[2]*xr[xi+2] + uf[4]*xr[xi+1]
                   + uf[6]*xr[xi]   + uf[8]*xr[xi-1] + uf[10]*xr[xi-2];
            } else {              // t even
                up = uf[1]*xr[xi+2] + uf[3]*xr[xi+1] + uf[5]*xr[xi]
                   + uf[7]*xr[xi-1] + uf[9]*xr[xi-2] + uf[11]*xr[xi-3];
            }
            const float sv = __sinf(up * ea);
            a[j] = fmaf(invb * sv, sv, up);
        }
    } else {
        // edge threads (nb==0 or nb==T-8): generic path, per-tap clamped global
        // loads (L2-resident; only 2 threads per row ever take this).
#pragma unroll
        for (int j = 0; j < 26; ++j) {
            int t = 2*nb - 5 + j;
            t = min(max(t, 0), 2*T - 1);
            const int s = t >> 1;
            const int par = t & 1;
            float xv7[7];
#pragma unroll
            for (int m = 0; m < 7; ++m) {
                int g = s - 3 + m;
                g = min(max(g, 0), T - 1);
                xv7[m] = xrow[g];
            }
            // xv7[3+d] == x[clamp(s+d)]
            const float upo = uf[0]*xv7[6] + uf[2]*xv7[5] + uf[4]*xv7[4]
                            + uf[6]*xv7[3] + uf[8]*xv7[2] + uf[10]*xv7[1];
            const float upe = uf[1]*xv7[5] + uf[3]*xv7[4] + uf[5]*xv7[3]
                            + uf[7]*xv7[2] + uf[9]*xv7[1] + uf[11]*xv7[0];
            const float up = par ? upo : upe;
            const float sv = __sinf(up * ea);
            a[j] = fmaf(invb * sv, sv, up);
        }
    }

    // down-conv: out[nb+d] = sum_k df[k] * a[2d+k]
    float o[W];
#pragma unroll
    for (int d = 0; d < W; ++d) {
        float acc = 0.0f;
#pragma unroll
        for (int k = 0; k < 12; ++k) acc = fmaf(df[k], a[2*d + k], acc);
        o[d] = acc;
    }
    float4* ov = (float4*)(out + rowoff + nb);
    ov[0] = make_float4(o[0], o[1], o[2], o[3]);
    ov[1] = make_float4(o[4], o[5], o[6], o[7]);
}

extern "C" void kernel_launch(void* const* d_in, const int* in_sizes, int n_in,
                              void* d_out, int out_size, void* d_ws, size_t ws_size,
                              hipStream_t stream) {
    const float* x  = (const float*)d_in[0];
    const float* uf = (const float*)d_in[1];
    const float* df = (const float*)d_in[2];
    const float* al = (const float*)d_in[3];
    const float* be = (const float*)d_in[4];
    float* outp = (float*)d_out;

    const int grid = B_N * C_CH * (T_LEN / (BLOCK * W));  // 32768
    act1d_kernel<<<grid, BLOCK, 0, stream>>>(x, uf, df, al, be, outp);
}